// Round 16
// baseline (490.722 us; speedup 1.0000x reference)
//
#include <hip/hip_runtime.h>
#include <cstdint>
#include <cstddef>

// SAGE-LSTM R27: persistent blocks + dynamic tile stealing for k_lstm_fused.
// R26 state: spill-free (12.500MB), 7-trans floor, BN=16, 473.5us. VALUBusy
// 53% / MfmaUtil 24% -> no pipe limit; residual is scheduling structure.
// Round-quantization model: 3125 blocks / 512 slots = 6.10 work-rounds but
// wall = ceil = 7 rounds (13% tail). 2-group ILP refuted by R21 data.
// R27: grid = 512 persistent blocks; tiles grabbed via device-scope atomicAdd
// (counters zeroed in k_pack_all each replay -> graph-capture safe). wreg
// (128KB/block W_hh frags) hoisted out of the tile loop (paid 512x not 3125x).
// Correct at ANY residency (dynamic stealing assumes no co-residency).
// Decision rules: lstm >= 192us -> model wrong, revert + declare ceiling;
// WRITE_SIZE > 13MB -> spill, revert.

constexpr int IN  = 128;
constexpr int DEG = 16;
#define LOG2E       1.4426950408889634f
#define TWO_LOG2E   2.8853900817779268f
#define NEG2_LOG2E -2.8853900817779268f

typedef short bf16x8 __attribute__((ext_vector_type(8)));
typedef float f32x4  __attribute__((ext_vector_type(4)));
typedef float f32x16 __attribute__((ext_vector_type(16)));
typedef unsigned int u32x4 __attribute__((ext_vector_type(4)));
typedef unsigned int u32x2 __attribute__((ext_vector_type(2)));

__device__ __forceinline__ float fsigmoid(float x) {   // unscaled input
    float e = __expf(-x);
    return __builtin_amdgcn_rcpf(1.0f + e);
}
__device__ __forceinline__ uint32_t pack2bf16(float a, float b) {
    uint32_t ua = __float_as_uint(a) + 0x8000u;
    uint32_t ub = __float_as_uint(b) + 0x8000u;
    return (ua >> 16) | (ub & 0xFFFF0000u);
}

// ---------- prep kernels ----------

// Pack all 4 [512 x 128] gate weights into MFMA fragment order, PRE-SCALED:
// gate rows i,f,o x log2e; gate g x 2log2e. Also zeroes the 2 tile counters.
__global__ void k_pack_all(const float* __restrict__ w0, u32x4* __restrict__ f0,
                           const float* __restrict__ w1, u32x4* __restrict__ f1,
                           const float* __restrict__ w2, u32x4* __restrict__ f2,
                           const float* __restrict__ w3, u32x4* __restrict__ f3,
                           uint32_t* __restrict__ counters) {
    int gt = blockIdx.x * 256 + threadIdx.x;     // 0..32767
    if (gt < 2) counters[gt] = 0u;               // re-zeroed every replay
    int which = gt >> 13;
    int tid  = gt & 8191;
    const float* wsrc = (which == 0) ? w0 : (which == 1) ? w1 : (which == 2) ? w2 : w3;
    u32x4* frag = (which == 0) ? f0 : (which == 1) ? f1 : (which == 2) ? f2 : f3;
    int lane = tid & 63;
    float v[8];
    int row;
    if ((which & 1) == 0) {
        int tile = (tid >> 6) & 15;
        int kst  = tid >> 10;
        row = tile * 32 + (lane & 31);
        int kbase = kst * 16 + (lane >> 5) * 8;
#pragma unroll
        for (int j = 0; j < 8; ++j) v[j] = wsrc[row * 128 + kbase + j];
    } else {
        int f  = tid >> 6;            // 0..127
        int ks = f & 3;
        int w8 = (f >> 2) & 7;
        int g  = f >> 5;
        row = g * 128 + w8 * 16 + (lane & 15);
        int kbase = ks * 32 + (lane >> 4) * 8;
#pragma unroll
        for (int j = 0; j < 8; ++j) v[j] = wsrc[row * 128 + kbase + j];
    }
    const float sc = ((row >> 7) == 2) ? TWO_LOG2E : LOG2E;
#pragma unroll
    for (int j = 0; j < 8; ++j) v[j] *= sc;
    u32x4 d;
    d.x = pack2bf16(v[0], v[1]);
    d.y = pack2bf16(v[2], v[3]);
    d.z = pack2bf16(v[4], v[5]);
    d.w = pack2bf16(v[6], v[7]);
    frag[tid] = d;
}

// Pack output-linear weights as A-frags over K=256 concat [Wself ; Wneigh].
__global__ void k_pack_out(const float* __restrict__ ws1, const float* __restrict__ wn1,
                           u32x4* __restrict__ f1,
                           const float* __restrict__ ws2, const float* __restrict__ wn2,
                           u32x4* __restrict__ f2) {
    int t = blockIdx.x * 256 + threadIdx.x;   // 0..6143
    int lane = t & 63;
    int row  = lane & 15;
    int kb   = (lane >> 4) * 8;
    float v[8];
    const float* ws; const float* wn; u32x4* dst; int p;
    if (t < 4096) { ws = ws1; wn = wn1; dst = f1; p = t; }
    else          { ws = ws2; wn = wn2; dst = f2; p = t - 4096; }
    int ks  = (p >> 6) & 7;
    int och = (p >> 9) * 16 + row;
    int kbase = ks * 32 + kb;
#pragma unroll
    for (int j = 0; j < 8; ++j) {
        int k = kbase + j;
        v[j] = (k < 128) ? ws[och * 128 + k] : wn[och * 128 + k - 128];
    }
    u32x4 d;
    d.x = pack2bf16(v[0], v[1]);
    d.y = pack2bf16(v[2], v[3]);
    d.z = pack2bf16(v[4], v[5]);
    d.w = pack2bf16(v[6], v[7]);
    dst[p] = d;
}

// ---------- kernel A: Xu = x @ W_ih^T + (b_ih+b_hh), gate-quad row store ----------
template <int CVT>
__global__ __launch_bounds__(256, 2) void k_xu(
    const void*   __restrict__ xin,     // CVT ? f32[N][128] : bf16[N][128]
    ushort*       __restrict__ xbf,     // CVT=1: bf16 copy out
    const u32x4*  __restrict__ wih,     // 8192 B-frags (32x32 layout, scaled)
    const float*  __restrict__ b_ih,    // [512]
    const float*  __restrict__ b_hh,    // [512]
    u32x2*        __restrict__ xu,      // [Nceil][128] u32x2 (1KB rows)
    int N)
{
    __shared__ u32x4 a_buf[16][66];

    const int tid   = threadIdx.x;
    const int lane  = tid & 63;
    const int w     = tid >> 6;
    const int mrow  = lane & 31;
    const int khalf = lane >> 5;
    const int node0 = blockIdx.x * 64;

    u32x4 wreg[8][4];
#pragma unroll
    for (int kst = 0; kst < 8; ++kst)
#pragma unroll
        for (int g = 0; g < 4; ++g)
            wreg[kst][g] = wih[(kst * 16 + g * 4 + w) * 64 + lane];

    float binit[4];
#pragma unroll
    for (int g = 0; g < 4; ++g) {
        int jj = g * 128 + w * 32 + mrow;
        binit[g] = (b_ih[jj] + b_hh[jj]) * ((g == 2) ? TWO_LOG2E : LOG2E);
    }

    {
        int m_st = tid >> 2, c4 = tid & 3;
        int gn = node0 + m_st; if (gn >= N) gn = N - 1;
        if constexpr (CVT) {
            const float* src = (const float*)xin + (size_t)gn * IN;
#pragma unroll
            for (int q = 0; q < 4; ++q) {
                int kg = q * 4 + c4;
                float4 f0 = *(const float4*)(src + kg * 8);
                float4 f1 = *(const float4*)(src + kg * 8 + 4);
                u32x4 d;
                d.x = pack2bf16(f0.x, f0.y);
                d.y = pack2bf16(f0.z, f0.w);
                d.z = pack2bf16(f1.x, f1.y);
                d.w = pack2bf16(f1.z, f1.w);
                a_buf[kg][m_st] = d;
                *(u32x4*)(xbf + (size_t)gn * IN + kg * 8) = d;
            }
        } else {
            const u32x4* src = (const u32x4*)((const ushort*)xin + (size_t)gn * IN);
#pragma unroll
            for (int q = 0; q < 4; ++q) {
                int kg = q * 4 + c4;
                a_buf[kg][m_st] = src[kg];
            }
        }
    }
    __syncthreads();

    const int coff = w * 32 + mrow;
#pragma unroll 1
    for (int Mt = 0; Mt < 2; ++Mt) {
        f32x16 acc[4];
#pragma unroll
        for (int g = 0; g < 4; ++g)
#pragma unroll
            for (int r = 0; r < 16; ++r) acc[g][r] = binit[g];

#pragma unroll
        for (int kst = 0; kst < 8; ++kst) {
            bf16x8 a = __builtin_bit_cast(bf16x8, a_buf[kst * 2 + khalf][Mt * 32 + mrow]);
#pragma unroll
            for (int g = 0; g < 4; ++g)
                acc[g] = __builtin_amdgcn_mfma_f32_32x32x16_bf16(
                    a, __builtin_bit_cast(bf16x8, wreg[kst][g]), acc[g], 0, 0, 0);
        }

#pragma unroll
        for (int r = 0; r < 16; ++r) {
            int m = Mt * 32 + (r & 3) + 8 * (r >> 2) + 4 * khalf;
            u32x2 d;
            d.x = pack2bf16(acc[0][r], acc[1][r]);
            d.y = pack2bf16(acc[2][r], acc[3][r]);
            xu[(size_t)(node0 + m) * 128 + coff] = d;
        }
    }
}

// ---------- kernel B: persistent recurrent LSTM (C^T, 16-node tiles) ----------
// 512 persistent blocks; tiles grabbed via atomicAdd on a device counter.
// wave w owns channels [w*16,w*16+16) of ALL 4 gates for 16 nodes; lane owns
// 4 adjacent channels of 1 node. h LDS: [node][ch] bf16, stride 272B.
template <int NOUT, int ACT, typename OutT>
__global__ __launch_bounds__(512, 4) void k_lstm_fused(
    const u32x2*  __restrict__ xu,      // 1KB gate-quad rows (scaled units)
    const int*    __restrict__ nbr,     // [N,16]
    const u32x4*  __restrict__ whh,     // 128 frags (A-operand, scaled)
    const u32x4*  __restrict__ wout,    // epilogue A-frags (K=256 concat)
    const float*  __restrict__ bout,    // [NOUT]
    const ushort* __restrict__ x_in,    // [N,128] bf16 (self input)
    OutT*         __restrict__ out,     // [N,NOUT]
    uint32_t*     __restrict__ counter, // dynamic tile counter
    int ntiles, int N)
{
    constexpr int HSTR = 272;                        // 17 x 16B, b128-aligned
    __shared__ alignas(16) char h_lds[2][16 * HSTR]; // 2 x 4.25KB
    __shared__ uint32_t idxs[DEG * 16];              // prescaled byte offsets
    __shared__ int tile_s;

    const int tid  = threadIdx.x;
    const int lane = tid & 63;
    const int w    = tid >> 6;
    const int col  = lane & 15;
    const int l4   = lane >> 4;

    // hoisted: W_hh A-frags (64 regs), loaded once per persistent block
    u32x4 wreg[4][4];
#pragma unroll
    for (int g = 0; g < 4; ++g)
#pragma unroll
        for (int ks = 0; ks < 4; ++ks)
            wreg[g][ks] = whh[((g * 8 + w) * 4 + ks) * 64 + lane];

    const char* xu_c = (const char*)xu;
    const uint32_t goff = (uint32_t)(w * 128 + l4 * 32);  // slice byte in xu row
    const int rd0 = col * HSTR + l4 * 16;                 // + ks*64
    const int wr0 = col * HSTR + w * 32 + l4 * 8;

    for (;;) {
        if (tid == 0) tile_s = (int)atomicAdd(counter, 1u);
        __syncthreads();   // tile_s visible; also WAR-guards h_lds vs prev epilogue
        const int tile = tile_s;
        if (tile >= ntiles) break;
        const int node0 = tile * 16;

        if (tid < DEG * 16) {               // idxs[t*16+m]
            int m = tid & 15, t = tid >> 4;
            int gn = node0 + m; if (gn >= N) gn = N - 1;
            idxs[t * 16 + m] = (uint32_t)nbr[gn * DEG + t] << 10;
        }
        if (tid < 16 * HSTR / 16)           // zero h(-1) = buf[0]
            ((u32x4*)h_lds[0])[tid] = u32x4{0u, 0u, 0u, 0u};

        float cst[4];
#pragma unroll
        for (int r = 0; r < 4; ++r) cst[r] = 0.0f;

        __syncthreads();   // idxs + h(-1) zeros visible

        // prologue gather (step 0): 32B contiguous per (node, ch-quad)
        u32x4 vv[2];
        {
            const char* p0 = xu_c + idxs[col] + goff;
            vv[0] = *(const u32x4*)(p0);
            vv[1] = *(const u32x4*)(p0 + 16);
        }

#pragma unroll 1
        for (int t = 0; t < DEG; ++t) {
            const char* hr = h_lds[t & 1];
            char*       hw = h_lds[(t + 1) & 1];

            // ---- acc init: C^T element (ch = w*16+l4*4+q, node = col)
            f32x4 acc[4];
#pragma unroll
            for (int q = 0; q < 4; ++q) {
                uint32_t px = vv[q >> 1][(q & 1) * 2];
                uint32_t py = vv[q >> 1][(q & 1) * 2 + 1];
                acc[0][q] = __uint_as_float(px << 16);
                acc[1][q] = __uint_as_float(px & 0xFFFF0000u);
                acc[2][q] = __uint_as_float(py << 16);
                acc[3][q] = __uint_as_float(py & 0xFFFF0000u);
            }

            // ---- prefetch next step (vv fully consumed)
            if (t + 1 < DEG) {
                const char* p0 = xu_c + idxs[(t + 1) * 16 + col] + goff;
                vv[0] = *(const u32x4*)(p0);
                vv[1] = *(const u32x4*)(p0 + 16);
            }

            // ---- MFMA C^T: A = W_hh frags, B = h(t-1) from LDS
#pragma unroll
            for (int ks = 0; ks < 4; ++ks) {
                bf16x8 b = *(const bf16x8*)(hr + rd0 + ks * 64);
#pragma unroll
                for (int g = 0; g < 4; ++g)
                    acc[g] = __builtin_amdgcn_mfma_f32_16x16x32_bf16(
                        __builtin_bit_cast(bf16x8, wreg[g][ks]), b, acc[g], 0, 0, 0);
            }

            // ---- cell: full c-path fold + folded output stage (7 trans)
            float hv[4];
#pragma unroll
            for (int q = 0; q < 4; ++q) {
                float Ei = __builtin_amdgcn_exp2f(-acc[0][q]);
                float Eg = __builtin_amdgcn_exp2f(-acc[2][q]);
                float Ef = __builtin_amdgcn_exp2f(-acc[1][q]);
                float p  = (1.0f + Ei) * (1.0f + Eg);
                float num = __fmaf_rn(cst[q], p, (1.0f - Eg) * (1.0f + Ef));
                float cv = num * __builtin_amdgcn_rcpf(p * (1.0f + Ef));
                cst[q] = cv;
                float Eo = __builtin_amdgcn_exp2f(-acc[3][q]);
                float Ec = __builtin_amdgcn_exp2f(cv * NEG2_LOG2E);
                hv[q] = (1.0f - Ec) *
                        __builtin_amdgcn_rcpf((1.0f + Eo) * (1.0f + Ec));
            }
            u32x2 hp;
            hp.x = pack2bf16(hv[0], hv[1]);
            hp.y = pack2bf16(hv[2], hv[3]);
            *(u32x2*)(hw + wr0) = hp;

            __syncthreads();   // h(t) visible; WAR-safe via dbuf
        }

        // ---- fused output linear: out = act([x|h] @ [Ws;Wn]^T + b)
        // h(15) in h_lds[0]. Next-tile zeroing is guarded by the loop-top barrier.
        if (NOUT == 128 || w < 4) {
            const char* hf = h_lds[0];
            const int otile = (NOUT == 128) ? w : (w & 3);
            const int och0  = otile * 16 + l4 * 4;
            const float4 bq = *(const float4*)(bout + och0);
            const int gn = node0 + col;
            const int gx = (gn < N) ? gn : (N - 1);
            f32x4 acc = {bq.x, bq.y, bq.z, bq.w};
#pragma unroll
            for (int ks = 0; ks < 8; ++ks) {
                u32x4 af = wout[(otile * 8 + ks) * 64 + lane];
                bf16x8 bf_;
                if (ks < 4)
                    bf_ = *(const bf16x8*)((const char*)x_in + (size_t)gx * 256 +
                                           ks * 64 + l4 * 16);
                else
                    bf_ = *(const bf16x8*)(hf + col * HSTR + (ks - 4) * 64 + l4 * 16);
                acc = __builtin_amdgcn_mfma_f32_16x16x32_bf16(
                    __builtin_bit_cast(bf16x8, af), bf_, acc, 0, 0, 0);
            }
            if (gn < N) {
                float av[4];
#pragma unroll
                for (int q = 0; q < 4; ++q)
                    av[q] = (ACT == 0) ? fmaxf(acc[q], 0.0f) : fsigmoid(acc[q]);
                if constexpr (sizeof(OutT) == 2) {
                    u32x2 o;
                    o.x = pack2bf16(av[0], av[1]);
                    o.y = pack2bf16(av[2], av[3]);
                    *(u32x2*)((ushort*)out + (size_t)gn * NOUT + och0) = o;
                } else {
                    f32x4 o = {av[0], av[1], av[2], av[3]};
                    *(f32x4*)((float*)out + (size_t)gn * NOUT + och0) = o;
                }
            }
        }
    }
}

extern "C" void kernel_launch(void* const* d_in, const int* in_sizes, int n_in,
                              void* d_out, int out_size, void* d_ws, size_t ws_size,
                              hipStream_t stream)
{
    const float* feats    = (const float*)d_in[0];
    const int*   nbr      = (const int*)  d_in[1];
    const float* w_ih1    = (const float*)d_in[2];
    const float* w_hh1    = (const float*)d_in[3];
    const float* b_ih1    = (const float*)d_in[4];
    const float* b_hh1    = (const float*)d_in[5];
    const float* w_self1  = (const float*)d_in[6];
    const float* w_neigh1 = (const float*)d_in[7];
    const float* b1       = (const float*)d_in[8];
    const float* w_ih2    = (const float*)d_in[9];
    const float* w_hh2    = (const float*)d_in[10];
    const float* b_ih2    = (const float*)d_in[11];
    const float* b_hh2    = (const float*)d_in[12];
    const float* w_self2  = (const float*)d_in[13];
    const float* w_neigh2 = (const float*)d_in[14];
    const float* b2       = (const float*)d_in[15];
    float* out = (float*)d_out;

    const int N = in_sizes[0] / IN;   // 50000
    const long long Nceil = (N + 63) & ~63LL;

    char* ws = (char*)d_ws;
    size_t off = 0;
    auto alloc = [&](size_t bytes) -> void* {
        void* p = (void*)(ws + off);
        off += (bytes + 255) & ~(size_t)255;
        return p;
    };
    u32x4*  wfrag_ih1 = (u32x4*)alloc(8192 * 16);
    u32x4*  wfrag_hh1 = (u32x4*)alloc(8192 * 16);
    u32x4*  wfrag_ih2 = (u32x4*)alloc(8192 * 16);
    u32x4*  wfrag_hh2 = (u32x4*)alloc(8192 * 16);
    u32x4*  wofrag1   = (u32x4*)alloc(4096 * 16);   // 64KB epilogue A-frags L1
    u32x4*  wofrag2   = (u32x4*)alloc(2048 * 16);   // 32KB epilogue A-frags L2
    uint32_t* counters = (uint32_t*)alloc(256);     // 2 tile counters
    ushort* feats_bf  = (ushort*)alloc((size_t)N * 128 * 2);
    ushort* out1      = (ushort*)alloc((size_t)N * 128 * 2);
    u32x2*  xu_buf    = (u32x2*)alloc((size_t)Nceil * 128 * 8);   // 51.25MB

    // prep (also zeroes the tile counters each replay)
    k_pack_all<<<dim3(128), dim3(256), 0, stream>>>(w_ih1, wfrag_ih1, w_hh1, wfrag_hh1,
                                                    w_ih2, wfrag_ih2, w_hh2, wfrag_hh2,
                                                    counters);
    k_pack_out<<<dim3(24), dim3(256), 0, stream>>>(w_self1, w_neigh1, wofrag1,
                                                   w_self2, w_neigh2, wofrag2);

    const int nblk64 = (int)(Nceil / 64);
    const int ntiles = (N + 15) / 16;   // 3125 (exact for N=50000)
    const int PERSIST = 512;            // 256 CU x 2 blocks/CU slot count

    // layer 1 (k_xu fuses the fp32->bf16 cast and emits feats_bf)
    k_xu<1><<<dim3(nblk64), dim3(256), 0, stream>>>(feats, feats_bf, wfrag_ih1, b_ih1, b_hh1, xu_buf, N);
    k_lstm_fused<128, 0, ushort><<<dim3(PERSIST), dim3(512), 0, stream>>>(
        xu_buf, nbr, wfrag_hh1, wofrag1, b1, feats_bf, out1, counters + 0, ntiles, N);

    // layer 2
    k_xu<0><<<dim3(nblk64), dim3(256), 0, stream>>>(out1, nullptr, wfrag_ih2, b_ih2, b_hh2, xu_buf, N);
    k_lstm_fused<64, 1, float><<<dim3(PERSIST), dim3(512), 0, stream>>>(
        xu_buf, nbr, wfrag_hh2, wofrag2, b2, out1, out, counters + 1, ntiles, N);
}